// Round 10
// baseline (1024.557 us; speedup 1.0000x reference)
//
#include <hip/hip_runtime.h>

typedef signed char char8v __attribute__((ext_vector_type(8)));
typedef signed char char4v __attribute__((ext_vector_type(4)));
typedef short short8 __attribute__((ext_vector_type(8)));
typedef int int32x4 __attribute__((ext_vector_type(4)));

static constexpr int DM = 2048;   // d_model
static constexpr int DF = 8192;   // d_ff
static constexpr int MT = 8192;   // B*S tokens
static constexpr int CH = 4096;   // M-chunk for stage 2
static constexpr double INVND = 1.0 / 16777216.0;  // 1/(DF*DM), double

// workspace layout (bytes); total ~184MB
static constexpr size_t OFF_STATS = 256;                           // 8192*2 f32
static constexpr size_t OFF_QX   = OFF_STATS + 65536;              // i8 [MT][DM]    16MB
static constexpr size_t OFF_QW1  = OFF_QX  + (size_t)MT * DM;      // i8 [DF][DM]    16MB
static constexpr size_t OFF_QW2  = OFF_QW1 + (size_t)DF * DM;      // i8 [DM][DF]    16MB
static constexpr size_t OFF_HACC = OFF_QW2 + (size_t)DM * DF;      // i16 [MT][DF]  128MB

__device__ __forceinline__ float waveSum(float v) {
#pragma unroll
  for (int o = 32; o > 0; o >>= 1) v += __shfl_xor(v, o, 64);
  return v;
}
__device__ __forceinline__ double waveSumD(double v) {
#pragma unroll
  for (int o = 32; o > 0; o >>= 1) v += __shfl_xor(v, o, 64);
  return v;
}
__device__ __forceinline__ float waveMax(float v) {
#pragma unroll
  for (int o = 32; o > 0; o >>= 1) v = fmaxf(v, __shfl_xor(v, o, 64));
  return v;
}
__device__ __forceinline__ float gelu_exact(float v) {
  return 0.5f * v * (1.0f + erff(v * 0.70710678118654752f));
}
__device__ __forceinline__ signed char q8(float v, float lo, float hi) {
  return (signed char)fminf(fmaxf(rintf(v), lo), hi);
}

__global__ __launch_bounds__(64) void zero_k(float* p) { p[threadIdx.x] = 0.f; }

// ---------------- sum(|w|) reduction (double accumulation -> deterministic beta) ----------------
__global__ __launch_bounds__(256) void abssum_k(const float4* __restrict__ w, int n4,
                                                double* __restrict__ out) {
  double s = 0.0;
  for (int i = blockIdx.x * 256 + threadIdx.x; i < n4; i += gridDim.x * 256) {
    float4 v = w[i];
    s += (double)fabsf(v.x) + (double)fabsf(v.y) + (double)fabsf(v.z) + (double)fabsf(v.w);
  }
  s = waveSumD(s);
  __shared__ double sm[4];
  if ((threadIdx.x & 63) == 0) sm[threadIdx.x >> 6] = s;
  __syncthreads();
  if (threadIdx.x == 0) atomicAdd(out, sm[0] + sm[1] + sm[2] + sm[3]);
}

// ---------------- layernorm stats + global absmax(x_ln) ----------------
__global__ __launch_bounds__(256) void ln_k(const float* __restrict__ x, const float* __restrict__ w,
                                            const float* __restrict__ b, float* __restrict__ stats,
                                            unsigned* __restrict__ amax) {
  __shared__ float sm[4];
  const int row = blockIdx.x, t = threadIdx.x;
  const float4* xr = (const float4*)(x + (size_t)row * DM);
  float4 v0 = xr[t], v1 = xr[t + 256];
  float s = v0.x + v0.y + v0.z + v0.w + v1.x + v1.y + v1.z + v1.w;
  s = waveSum(s);
  if ((t & 63) == 0) sm[t >> 6] = s;
  __syncthreads();
  const float mu = (sm[0] + sm[1] + sm[2] + sm[3]) * (1.0f / DM);
  __syncthreads();
  float d[8] = {v0.x - mu, v0.y - mu, v0.z - mu, v0.w - mu,
                v1.x - mu, v1.y - mu, v1.z - mu, v1.w - mu};
  float sq = 0.f;
#pragma unroll
  for (int i = 0; i < 8; i++) sq += d[i] * d[i];
  sq = waveSum(sq);
  if ((t & 63) == 0) sm[t >> 6] = sq;
  __syncthreads();
  const float var = (sm[0] + sm[1] + sm[2] + sm[3]) * (1.0f / DM);
  const float rstd = 1.0f / sqrtf(var + 1e-5f);
  __syncthreads();
  const float4* wr = (const float4*)w;
  const float4* br = (const float4*)b;
  float4 w0 = wr[t], w1v = wr[t + 256], b0 = br[t], b1v = br[t + 256];
  float m = 0.f;
  m = fmaxf(m, fabsf(d[0] * rstd * w0.x + b0.x));
  m = fmaxf(m, fabsf(d[1] * rstd * w0.y + b0.y));
  m = fmaxf(m, fabsf(d[2] * rstd * w0.z + b0.z));
  m = fmaxf(m, fabsf(d[3] * rstd * w0.w + b0.w));
  m = fmaxf(m, fabsf(d[4] * rstd * w1v.x + b1v.x));
  m = fmaxf(m, fabsf(d[5] * rstd * w1v.y + b1v.y));
  m = fmaxf(m, fabsf(d[6] * rstd * w1v.z + b1v.z));
  m = fmaxf(m, fabsf(d[7] * rstd * w1v.w + b1v.w));
  m = waveMax(m);
  if ((t & 63) == 0) sm[t >> 6] = m;
  __syncthreads();
  if (t == 0) {
    float mm = fmaxf(fmaxf(sm[0], sm[1]), fmaxf(sm[2], sm[3]));
    stats[2 * row] = mu;
    stats[2 * row + 1] = rstd;
    atomicMax(amax, __float_as_uint(mm));
  }
}

// ---------------- quantize activations -> int8 ----------------
__global__ __launch_bounds__(256) void quantx_k(const float* __restrict__ x, const float* __restrict__ w,
                                                const float* __restrict__ b, const float* __restrict__ stats,
                                                const float* __restrict__ fam, signed char* __restrict__ qx) {
  const int row = blockIdx.x, t = threadIdx.x;
  const float mu = stats[2 * row], rstd = stats[2 * row + 1];
  const float sc = 127.0f / fmaxf(fam[0], 1e-5f);
  const float4* xr = (const float4*)(x + (size_t)row * DM);
  const float4* wr = (const float4*)w;
  const float4* br = (const float4*)b;
  float4 v0 = xr[2 * t], v1 = xr[2 * t + 1];
  float4 w0 = wr[2 * t], w1v = wr[2 * t + 1];
  float4 b0 = br[2 * t], b1v = br[2 * t + 1];
  char8v o;
  o[0] = q8(((v0.x - mu) * rstd * w0.x + b0.x) * sc, -127.f, 127.f);
  o[1] = q8(((v0.y - mu) * rstd * w0.y + b0.y) * sc, -127.f, 127.f);
  o[2] = q8(((v0.z - mu) * rstd * w0.z + b0.z) * sc, -127.f, 127.f);
  o[3] = q8(((v0.w - mu) * rstd * w0.w + b0.w) * sc, -127.f, 127.f);
  o[4] = q8(((v1.x - mu) * rstd * w1v.x + b1v.x) * sc, -127.f, 127.f);
  o[5] = q8(((v1.y - mu) * rstd * w1v.y + b1v.y) * sc, -127.f, 127.f);
  o[6] = q8(((v1.z - mu) * rstd * w1v.z + b1v.z) * sc, -127.f, 127.f);
  o[7] = q8(((v1.w - mu) * rstd * w1v.w + b1v.w) * sc, -127.f, 127.f);
  *(char8v*)(qx + (size_t)row * DM + t * 8) = o;
}

// ---------------- ternarize weights -> int8 ----------------
__global__ __launch_bounds__(256) void quantw_k(const float4* __restrict__ w,
                                                const double* __restrict__ sumabs,
                                                signed char* __restrict__ qw, int n4) {
  const float beta = fmaxf((float)(sumabs[0] * INVND), 1e-5f);
  const float rb = 1.0f / beta;
  for (int i = blockIdx.x * 256 + threadIdx.x; i < n4; i += gridDim.x * 256) {
    float4 v = w[i];
    char4v o;
    o[0] = q8(v.x * rb, -1.f, 1.f);
    o[1] = q8(v.y * rb, -1.f, 1.f);
    o[2] = q8(v.z * rb, -1.f, 1.f);
    o[3] = q8(v.w * rb, -1.f, 1.f);
    *(char4v*)(qw + (size_t)i * 4) = o;
  }
}

// ---------------- quantize h chunk: gelu(s1*acc) -> int8 ----------------
__global__ __launch_bounds__(256) void quanth_k(const short8* __restrict__ hacc,
                                                const double* __restrict__ dsum,
                                                const float* __restrict__ fam,
                                                signed char* __restrict__ qh, int n8) {
  const float beta = fmaxf((float)(dsum[0] * INVND), 1e-5f);
  const float s1 = beta * fmaxf(fam[0], 1e-5f) * (1.0f / 127.0f);
  const float sc2 = 127.0f / fmaxf(fam[1], 1e-5f);
  for (int i = blockIdx.x * 256 + threadIdx.x; i < n8; i += gridDim.x * 256) {
    short8 v = hacc[i];
    char8v o;
#pragma unroll
    for (int j = 0; j < 8; j++) {
      const float g = gelu_exact((float)v[j] * s1);
      o[j] = q8(g * sc2, -127.f, 127.f);
    }
    *(char8v*)(qh + (size_t)i * 8) = o;
  }
}

// ---------------- GEMM: C[M][N] = A[M][K] * B[N][K]^T, exact int8 MFMA ----------------
// Double-buffered LDS, prefetch-before-compute, counted vmcnt (T3-minimal).
// EPI=1: store raw acc as int16 + amax(gelu(acc*s)); EPI=0: store f32 acc*s
__device__ __forceinline__ void gll16(const signed char* g, signed char* l) {
  __builtin_amdgcn_global_load_lds((const __attribute__((address_space(1))) void*)g,
                                   (__attribute__((address_space(3))) void*)l, 16, 0, 0);
}

template <int EPI>
__global__ __launch_bounds__(256, 4) void gemm_i8(const signed char* __restrict__ A,
                                                  const signed char* __restrict__ B,
                                                  void* __restrict__ Cv, int M, int N, int K,
                                                  int bandrows,
                                                  const double* __restrict__ p_sumw,
                                                  const float* __restrict__ p_amax,
                                                  unsigned* __restrict__ amax_out) {
  // double buffer: buf b at smem + b*16384; As [0,8K), Bs [8K,16K) within a buffer
  __shared__ __align__(16) signed char smem[32768];
  const int tid = threadIdx.x;
  const int wid = tid >> 6, lane = tid & 63;

  // L2-blocked band decomposition: XCD (= bid&7) owns 'bandrows' contiguous tile-rows,
  // traversed column-major so the A-band stays L2-resident per XCD.
  const int xcd = (int)blockIdx.x & 7;
  const int idx = (int)blockIdx.x >> 3;
  const int by = xcd * bandrows + (idx % bandrows);
  const int bx = idx / bandrows;
  const int m0 = by * 128, n0 = bx * 128;
  const int wm = (wid >> 1) * 64, wn = (wid & 1) * 64;

  int32x4 acc[4][4];
#pragma unroll
  for (int i = 0; i < 4; i++)
#pragma unroll
    for (int j = 0; j < 4; j++) acc[i][j] = int32x4{0, 0, 0, 0};

  // staging: thread t -> row t/4 (+64 on 2nd issue), byte-col (t&3)*16
  const int srow = tid >> 2;
  const int scol = (tid & 3) * 16;
  const signed char* gA = A + (size_t)(m0 + srow) * K + scol;
  const signed char* gB = B + (size_t)(n0 + srow) * K + scol;
  const size_t rowK64 = (size_t)64 * K;

  // fragment LDS byte offsets: lane = 16q + r -> row r, k-bytes [16q,16q+16)
  const int lrow = lane & 15;
  const int lkb = (lane >> 4) * 16;
  const int aoff = (wm + lrow) * 64 + lkb;
  const int boff = (wn + lrow) * 64 + lkb;

#define STAGE(buf, k0)                                            \
  {                                                               \
    signed char* base_ = smem + ((buf) << 14);                    \
    gll16(gA + (k0), base_ + wid * 1024);                         \
    gll16(gA + (k0) + rowK64, base_ + 4096 + wid * 1024);         \
    gll16(gB + (k0), base_ + 8192 + wid * 1024);                  \
    gll16(gB + (k0) + rowK64, base_ + 12288 + wid * 1024);        \
  }

  STAGE(0, 0);
  int cur = 0;
  for (int k0 = 0; k0 < K; k0 += 64) {
    if (k0 + 64 < K) {
      STAGE(cur ^ 1, k0 + 64);  // next tile in flight during this tile's MFMA
      asm volatile("s_waitcnt vmcnt(4)" ::: "memory");  // cur's 4 loads done; next's stay
    } else {
      asm volatile("s_waitcnt vmcnt(0)" ::: "memory");
    }
    __builtin_amdgcn_s_barrier();
    asm volatile("" ::: "memory");

    const signed char* Ab = smem + (cur << 14);
    const signed char* Bb = Ab + 8192;
    int32x4 af[4], bfv[4];
#pragma unroll
    for (int m = 0; m < 4; m++) af[m] = *(const int32x4*)(Ab + aoff + m * 1024);
#pragma unroll
    for (int n = 0; n < 4; n++) bfv[n] = *(const int32x4*)(Bb + boff + n * 1024);
#pragma unroll
    for (int m = 0; m < 4; m++)
#pragma unroll
      for (int n = 0; n < 4; n++)
        acc[m][n] = __builtin_amdgcn_mfma_i32_16x16x64_i8(af[m], bfv[n], acc[m][n], 0, 0, 0);

    asm volatile("" ::: "memory");
    __builtin_amdgcn_s_barrier();  // all waves done reading cur before it is restaged
    cur ^= 1;
  }
#undef STAGE

  const float beta = fmaxf((float)(p_sumw[0] * INVND), 1e-5f);
  const float s = beta * fmaxf(p_amax[0], 1e-5f) * (1.0f / 127.0f);
  const int crow0 = m0 + wm + ((lane >> 4) << 2);
  const int ccol0 = n0 + wn + (lane & 15);

  if (EPI == 1) {
    float lmax = 0.f;
#pragma unroll
    for (int m = 0; m < 4; m++)
#pragma unroll
      for (int n = 0; n < 4; n++)
#pragma unroll
        for (int j = 0; j < 4; j++)
          lmax = fmaxf(lmax, fabsf(gelu_exact((float)acc[m][n][j] * s)));
    lmax = waveMax(lmax);
    if (lane == 0) atomicMax(amax_out, __float_as_uint(lmax));
    // line-completing store order: the 4 n-stores of one row hit the same 128B line
#pragma unroll
    for (int m = 0; m < 4; m++) {
#pragma unroll
      for (int j = 0; j < 4; j++) {
        const size_t rowb = (size_t)(crow0 + m * 16 + j) * N + ccol0;
#pragma unroll
        for (int n = 0; n < 4; n++) {
          const float a = (float)acc[m][n][j];
          ((short*)Cv)[rowb + n * 16] = (short)fminf(fmaxf(a, -32767.f), 32767.f);
        }
      }
    }
  } else {
#pragma unroll
    for (int m = 0; m < 4; m++) {
#pragma unroll
      for (int j = 0; j < 4; j++) {
        const size_t rowb = (size_t)(crow0 + m * 16 + j) * N + ccol0;
#pragma unroll
        for (int n = 0; n < 4; n++)
          ((float*)Cv)[rowb + n * 16] = (float)acc[m][n][j] * s;
      }
    }
  }
}

extern "C" void kernel_launch(void* const* d_in, const int* in_sizes, int n_in,
                              void* d_out, int out_size, void* d_ws, size_t ws_size,
                              hipStream_t stream) {
  const float* x = (const float*)d_in[0];
  const float* lnw = (const float*)d_in[1];
  const float* lnb = (const float*)d_in[2];
  const float* w1 = (const float*)d_in[3];
  const float* w2 = (const float*)d_in[4];
  float* out = (float*)d_out;

  char* ws = (char*)d_ws;
  double* dsum = (double*)ws;             // [0]=sum|w1| [1]=sum|w2|
  float* fam = (float*)(ws + 16);         // [0]=amax_x [1]=amax_h
  float* stats = (float*)(ws + OFF_STATS);
  signed char* qx = (signed char*)(ws + OFF_QX);
  signed char* qw1 = (signed char*)(ws + OFF_QW1);
  signed char* qw2 = (signed char*)(ws + OFF_QW2);
  short* hacc = (short*)(ws + OFF_HACC);
  signed char* qh = (signed char*)(ws + OFF_QX);  // reuses qx+qw1 after GEMM1

  zero_k<<<1, 64, 0, stream>>>((float*)ws);
  abssum_k<<<2048, 256, 0, stream>>>((const float4*)w1, (DF * DM) / 4, &dsum[0]);
  abssum_k<<<2048, 256, 0, stream>>>((const float4*)w2, (DM * DF) / 4, &dsum[1]);
  ln_k<<<MT, 256, 0, stream>>>(x, lnw, lnb, stats, (unsigned*)&fam[0]);
  quantx_k<<<MT, 256, 0, stream>>>(x, lnw, lnb, stats, fam, qx);
  quantw_k<<<2048, 256, 0, stream>>>((const float4*)w1, &dsum[0], qw1, (DF * DM) / 4);
  quantw_k<<<2048, 256, 0, stream>>>((const float4*)w2, &dsum[1], qw2, (DM * DF) / 4);

  // GEMM1: M=8192, N=8192, K=2048 -> hacc int16 + amax_h. bands: 64 tile-rows / 8 XCDs = 8
  gemm_i8<1><<<dim3((DF / 128) * (MT / 128)), 256, 0, stream>>>(qx, qw1, hacc, MT, DF, DM,
                                                                MT / 128 / 8, &dsum[0], &fam[0],
                                                                (unsigned*)&fam[1]);
  // stage 2 in two chunks: quantize h -> qh (int8), GEMM2 -> out. bands: 32/8 = 4
  for (int c = 0; c < MT / CH; c++) {
    quanth_k<<<2048, 256, 0, stream>>>((const short8*)(hacc + (size_t)c * CH * DF), &dsum[0], fam,
                                       qh, (CH * DF) / 8);
    gemm_i8<0><<<dim3((DM / 128) * (CH / 128)), 256, 0, stream>>>(qh, qw2, out + (size_t)c * CH * DM,
                                                                  CH, DM, DF, CH / 128 / 8,
                                                                  &dsum[1], &fam[1], nullptr);
  }
}